// Round 1
// 726.991 us; speedup vs baseline: 1.0492x; 1.0492x over previous
//
#include <hip/hip_runtime.h>

// 2-layer GCN encoder + 2 MLP decoders.
//   N = 100000, E = 1600000, NFEAT = 128, NHID = 64, DEC_HID = 128
// Outputs: h [N,64] | x_hat [N,128] | m_hat [N,128], fp32, concatenated in d_out.
//
// R3: CSR gather replaced scatter atomics: 1615 -> 1131 us.
// R4: hierarchical scan: 1131 -> 918 us.
// R5: two-level LDS counting sort for CSR build; float4 gathers. 918 -> 762 us.
// R6: 4x4 register-tiled fp32 GEMMs (mlp2 + gemm64). Old inner loops issued
//     1 LDS read per FMA (35% of VALU slots were FMA -> 43 TF eff). New: 16
//     FMA per 4 LDS broadcast reads + 1 float4 weight load.

#define BUCK_SHIFT 7
#define BUCK_W 128
#define MAXB 1024
#define EMIT_CHUNK 8192

// ---------------- CSR build: two-level counting sort ----------------

// K1: per-bucket edge counts (LDS-aggregated histogram)
__global__ __launch_bounds__(256) void bucket_count(const int* __restrict__ dst,
                                                    int* __restrict__ bucketCnt,
                                                    int E, int NBUCK) {
    __shared__ int h[MAXB];
    for (int i = threadIdx.x; i < NBUCK; i += 256) h[i] = 0;
    __syncthreads();
    for (long long e = (long long)blockIdx.x * blockDim.x + threadIdx.x; e < E;
         e += (long long)gridDim.x * blockDim.x)
        atomicAdd(&h[dst[e] >> BUCK_SHIFT], 1);
    __syncthreads();
    for (int i = threadIdx.x; i < NBUCK; i += 256)
        if (h[i]) atomicAdd(&bucketCnt[i], h[i]);
}

// K2: exclusive scan of bucket counts (NBUCK <= 1024)
__global__ __launch_bounds__(1024) void bucket_scan(const int* __restrict__ cnt,
                                                    int* __restrict__ off,
                                                    int* __restrict__ cur,
                                                    int NBUCK, int E) {
    __shared__ int s[1024];
    const int t = threadIdx.x;
    int v = (t < NBUCK) ? cnt[t] : 0;
    s[t] = v;
    __syncthreads();
    for (int o = 1; o < 1024; o <<= 1) {
        int u = (t >= o) ? s[t - o] : 0;
        __syncthreads();
        s[t] += u;
        __syncthreads();
    }
    if (t < NBUCK) { off[t] = s[t] - v; cur[t] = s[t] - v; }
    if (t == 0) off[NBUCK] = E;
}

// K3: emit (src,dst) pairs into bucket-ordered staging with block-reserved runs
__global__ __launch_bounds__(256) void bucket_emit(const int* __restrict__ src,
                                                   const int* __restrict__ dst,
                                                   int* __restrict__ bucketCursor,
                                                   uint2* __restrict__ staging,
                                                   int E, int NBUCK) {
    __shared__ int h[MAXB];
    const int t = threadIdx.x;
    const long long base = (long long)blockIdx.x * EMIT_CHUNK;
    for (int i = t; i < NBUCK; i += 256) h[i] = 0;
    __syncthreads();
#pragma unroll
    for (int i = 0; i < EMIT_CHUNK / 256; ++i) {
        long long e = base + t + i * 256;
        if (e < E) atomicAdd(&h[dst[e] >> BUCK_SHIFT], 1);
    }
    __syncthreads();
    for (int i = t; i < NBUCK; i += 256) {
        int c = h[i];
        h[i] = c ? atomicAdd(&bucketCursor[i], c) : 0;
    }
    __syncthreads();
#pragma unroll
    for (int i = 0; i < EMIT_CHUNK / 256; ++i) {
        long long e = base + t + i * 256;
        if (e < E) {
            int d = dst[e];
            int pos = atomicAdd(&h[d >> BUCK_SHIFT], 1);
            staging[pos] = make_uint2((unsigned)src[e], (unsigned)d);
        }
    }
}

// K4: per-bucket counting sort -> rowStart + adj (one block per bucket)
__global__ __launch_bounds__(256) void bucket_sort(const uint2* __restrict__ staging,
                                                   const int* __restrict__ bucketOff,
                                                   int* __restrict__ rowStart,
                                                   int* __restrict__ adj,
                                                   int N, int NBUCK, int E) {
    __shared__ int h[BUCK_W];
    __shared__ int cur[BUCK_W];
    const int b = blockIdx.x;
    const int t = threadIdx.x;
    const int lo = b << BUCK_SHIFT;
    const int off = bucketOff[b];
    const int M = bucketOff[b + 1] - off;
    if (t < BUCK_W) h[t] = 0;
    __syncthreads();
    for (int i = t; i < M; i += 256)
        atomicAdd(&h[(int)staging[off + i].y - lo], 1);
    __syncthreads();
    if (t < BUCK_W) cur[t] = h[t];
    __syncthreads();
    for (int o = 1; o < BUCK_W; o <<= 1) {
        int u = 0;
        if (t < BUCK_W && t >= o) u = cur[t - o];
        __syncthreads();
        if (t < BUCK_W) cur[t] += u;
        __syncthreads();
    }
    if (t < BUCK_W) {
        int ex = off + cur[t] - h[t];     // exclusive prefix within bucket
        int d = lo + t;
        if (d < N) rowStart[d] = ex;
        cur[t] = ex;
    }
    if (b == 0 && t == 0) rowStart[N] = E;
    __syncthreads();
    for (int i = t; i < M; i += 256) {
        uint2 p = staging[off + i];
        int pos = atomicAdd(&cur[(int)p.y - lo], 1);
        adj[pos] = (int)p.x;
    }
}

__global__ void dinv_kernel(const int* __restrict__ rowStart, float* __restrict__ dinv, int N) {
    int i = blockIdx.x * blockDim.x + threadIdx.x;
    if (i < N) {
        int deg = rowStart[i + 1] - rowStart[i];
        dinv[i] = rsqrtf((float)deg + 1.0f);
    }
}

// ---------------- GEMM: out[N,64] = A[N,K] @ W[K,64] ----------------
// 64 rows x 64 cols per block; each thread owns a 4x4 register tile.
// As padded to K+1 so the 4 row-group broadcast reads hit distinct banks.
template <int K>
__global__ __launch_bounds__(256) void gemm64(const float* __restrict__ A,
                                              const float* __restrict__ W,
                                              float* __restrict__ out, int N) {
    const int tx = threadIdx.x;
    const int c4 = (tx & 15) << 2;        // output col base 0..60
    const int rg = (tx >> 4) << 2;        // row base within tile 0..60
    const int row0 = blockIdx.x * 64;
    __shared__ float As[64][K + 1];
    constexpr int C4 = K / 4;             // float4 per row
    for (int idx = tx; idx < 64 * C4; idx += 256) {
        int r = idx / C4, c = idx - r * C4;
        int row = row0 + r;
        float4 v = (row < N) ? ((const float4*)A)[(long long)row * C4 + c]
                             : make_float4(0.f, 0.f, 0.f, 0.f);
        As[r][c * 4 + 0] = v.x;
        As[r][c * 4 + 1] = v.y;
        As[r][c * 4 + 2] = v.z;
        As[r][c * 4 + 3] = v.w;
    }
    __syncthreads();
    float acc[4][4];
#pragma unroll
    for (int r = 0; r < 4; ++r)
#pragma unroll
        for (int j = 0; j < 4; ++j) acc[r][j] = 0.f;
#pragma unroll 4
    for (int k = 0; k < K; ++k) {
        float4 w = *(const float4*)&W[k * 64 + c4];
        float a0 = As[rg + 0][k];
        float a1 = As[rg + 1][k];
        float a2 = As[rg + 2][k];
        float a3 = As[rg + 3][k];
        acc[0][0] += a0 * w.x; acc[0][1] += a0 * w.y; acc[0][2] += a0 * w.z; acc[0][3] += a0 * w.w;
        acc[1][0] += a1 * w.x; acc[1][1] += a1 * w.y; acc[1][2] += a1 * w.z; acc[1][3] += a1 * w.w;
        acc[2][0] += a2 * w.x; acc[2][1] += a2 * w.y; acc[2][2] += a2 * w.z; acc[2][3] += a2 * w.w;
        acc[3][0] += a3 * w.x; acc[3][1] += a3 * w.y; acc[3][2] += a3 * w.z; acc[3][3] += a3 * w.w;
    }
#pragma unroll
    for (int r = 0; r < 4; ++r) {
        int row = row0 + rg + r;
        if (row < N)
            *(float4*)&out[(long long)row * 64 + c4] =
                make_float4(acc[r][0], acc[r][1], acc[r][2], acc[r][3]);
    }
}

// ---------------- GCN aggregation by gather, float4 lanes ----------------
// 16 lanes per dst row (lane l owns features 4l..4l+3).
// out = dinv[d]*(m[d]*dinv[d] + sum m[s]*dinv[s])
template <int RELU>
__global__ __launch_bounds__(256) void gather_combine4(const float4* __restrict__ m4,
                                                       const int* __restrict__ rowStart,
                                                       const int* __restrict__ adj,
                                                       const float* __restrict__ dinv,
                                                       float4* __restrict__ out4, int N) {
    int gid = blockIdx.x * 256 + threadIdx.x;
    int d = gid >> 4;
    if (d >= N) return;
    int l = gid & 15;
    int start = rowStart[d], end = rowStart[d + 1];
    float dv = dinv[d];
    float4 ms = m4[(long long)d * 16 + l];
    float4 a0, a1;
    a0.x = ms.x * dv; a0.y = ms.y * dv; a0.z = ms.z * dv; a0.w = ms.w * dv;
    a1.x = 0.f; a1.y = 0.f; a1.z = 0.f; a1.w = 0.f;
    int t = start;
    for (; t + 2 <= end; t += 2) {
        int s0 = adj[t], s1 = adj[t + 1];
        float w0 = dinv[s0], w1 = dinv[s1];
        float4 v0 = m4[(long long)s0 * 16 + l];
        float4 v1 = m4[(long long)s1 * 16 + l];
        a0.x += v0.x * w0; a0.y += v0.y * w0; a0.z += v0.z * w0; a0.w += v0.w * w0;
        a1.x += v1.x * w1; a1.y += v1.y * w1; a1.z += v1.z * w1; a1.w += v1.w * w1;
    }
    if (t < end) {
        int s = adj[t];
        float w = dinv[s];
        float4 v = m4[(long long)s * 16 + l];
        a0.x += v.x * w; a0.y += v.y * w; a0.z += v.z * w; a0.w += v.w * w;
    }
    float4 r;
    r.x = (a0.x + a1.x) * dv; r.y = (a0.y + a1.y) * dv;
    r.z = (a0.z + a1.z) * dv; r.w = (a0.w + a1.w) * dv;
    if (RELU) {
        r.x = fmaxf(r.x, 0.f); r.y = fmaxf(r.y, 0.f);
        r.z = fmaxf(r.z, 0.f); r.w = fmaxf(r.w, 0.f);
    }
    out4[(long long)d * 16 + l] = r;
}

// neighbor mean: out = (sum_{s in N(d)} h[s]) / max(deg,1)
__global__ __launch_bounds__(256) void gather_mean4(const float4* __restrict__ h4,
                                                    const int* __restrict__ rowStart,
                                                    const int* __restrict__ adj,
                                                    float4* __restrict__ out4, int N) {
    int gid = blockIdx.x * 256 + threadIdx.x;
    int d = gid >> 4;
    if (d >= N) return;
    int l = gid & 15;
    int start = rowStart[d], end = rowStart[d + 1];
    int deg = end - start;
    float4 a0, a1;
    a0.x = 0.f; a0.y = 0.f; a0.z = 0.f; a0.w = 0.f;
    a1 = a0;
    int t = start;
    for (; t + 2 <= end; t += 2) {
        int s0 = adj[t], s1 = adj[t + 1];
        float4 v0 = h4[(long long)s0 * 16 + l];
        float4 v1 = h4[(long long)s1 * 16 + l];
        a0.x += v0.x; a0.y += v0.y; a0.z += v0.z; a0.w += v0.w;
        a1.x += v1.x; a1.y += v1.y; a1.z += v1.z; a1.w += v1.w;
    }
    if (t < end) {
        float4 v = h4[(long long)adj[t] * 16 + l];
        a0.x += v.x; a0.y += v.y; a0.z += v.z; a0.w += v.w;
    }
    float inv = 1.0f / (float)max(deg, 1);
    float4 r;
    r.x = (a0.x + a1.x) * inv; r.y = (a0.y + a1.y) * inv;
    r.z = (a0.z + a1.z) * inv; r.w = (a0.w + a1.w) * inv;
    out4[(long long)d * 16 + l] = r;
}

// ---------------- fused 2-layer MLP: out = relu(In@Wa + ba) @ Wb + bb ----------------
// 32 rows x 128 cols per block, 256 threads, 4x4 register tile per thread.
// LDS broadcast reads are 2 distinct addresses per wave (2-way = free).
__global__ __launch_bounds__(256) void mlp2_kernel(const float* __restrict__ In,
                                                   const float* __restrict__ Wa,
                                                   const float* __restrict__ ba,
                                                   const float* __restrict__ Wb,
                                                   const float* __restrict__ bb,
                                                   float* __restrict__ out, int N) {
    const int tx = threadIdx.x;
    const int c4 = (tx & 31) << 2;       // output col base 0..124
    const int rg = (tx >> 5) << 2;       // row base within tile 0..28
    const int row0 = blockIdx.x * 32;
    __shared__ float ins[32][64];
    __shared__ float t[32][128];
    for (int idx = tx; idx < 32 * 16; idx += 256) {
        int r = idx >> 4, c = idx & 15;
        int row = row0 + r;
        float4 v = (row < N) ? ((const float4*)In)[(long long)row * 16 + c]
                             : make_float4(0.f, 0.f, 0.f, 0.f);
        *(float4*)&ins[r][c * 4] = v;
    }
    __syncthreads();
    float acc[4][4];
    float4 b1 = *(const float4*)&ba[c4];
#pragma unroll
    for (int r = 0; r < 4; ++r) {
        acc[r][0] = b1.x; acc[r][1] = b1.y; acc[r][2] = b1.z; acc[r][3] = b1.w;
    }
#pragma unroll 4
    for (int k = 0; k < 64; ++k) {
        float4 w = *(const float4*)&Wa[k * 128 + c4];
        float a0 = ins[rg + 0][k];
        float a1 = ins[rg + 1][k];
        float a2 = ins[rg + 2][k];
        float a3 = ins[rg + 3][k];
        acc[0][0] += a0 * w.x; acc[0][1] += a0 * w.y; acc[0][2] += a0 * w.z; acc[0][3] += a0 * w.w;
        acc[1][0] += a1 * w.x; acc[1][1] += a1 * w.y; acc[1][2] += a1 * w.z; acc[1][3] += a1 * w.w;
        acc[2][0] += a2 * w.x; acc[2][1] += a2 * w.y; acc[2][2] += a2 * w.z; acc[2][3] += a2 * w.w;
        acc[3][0] += a3 * w.x; acc[3][1] += a3 * w.y; acc[3][2] += a3 * w.z; acc[3][3] += a3 * w.w;
    }
#pragma unroll
    for (int r = 0; r < 4; ++r)
        *(float4*)&t[rg + r][c4] = make_float4(fmaxf(acc[r][0], 0.f), fmaxf(acc[r][1], 0.f),
                                               fmaxf(acc[r][2], 0.f), fmaxf(acc[r][3], 0.f));
    __syncthreads();
    float4 b2 = *(const float4*)&bb[c4];
#pragma unroll
    for (int r = 0; r < 4; ++r) {
        acc[r][0] = b2.x; acc[r][1] = b2.y; acc[r][2] = b2.z; acc[r][3] = b2.w;
    }
#pragma unroll 4
    for (int k = 0; k < 128; ++k) {
        float4 w = *(const float4*)&Wb[k * 128 + c4];
        float a0 = t[rg + 0][k];
        float a1 = t[rg + 1][k];
        float a2 = t[rg + 2][k];
        float a3 = t[rg + 3][k];
        acc[0][0] += a0 * w.x; acc[0][1] += a0 * w.y; acc[0][2] += a0 * w.z; acc[0][3] += a0 * w.w;
        acc[1][0] += a1 * w.x; acc[1][1] += a1 * w.y; acc[1][2] += a1 * w.z; acc[1][3] += a1 * w.w;
        acc[2][0] += a2 * w.x; acc[2][1] += a2 * w.y; acc[2][2] += a2 * w.z; acc[2][3] += a2 * w.w;
        acc[3][0] += a3 * w.x; acc[3][1] += a3 * w.y; acc[3][2] += a3 * w.z; acc[3][3] += a3 * w.w;
    }
#pragma unroll
    for (int r = 0; r < 4; ++r) {
        int row = row0 + rg + r;
        if (row < N)
            *(float4*)&out[(long long)row * 128 + c4] =
                make_float4(acc[r][0], acc[r][1], acc[r][2], acc[r][3]);
    }
}

extern "C" void kernel_launch(void* const* d_in, const int* in_sizes, int n_in,
                              void* d_out, int out_size, void* d_ws, size_t ws_size,
                              hipStream_t stream) {
    const float* x   = (const float*)d_in[0];
    const int*   ei  = (const int*)  d_in[1];
    const float* W1  = (const float*)d_in[2];
    const float* W2  = (const float*)d_in[3];
    const float* Wx1 = (const float*)d_in[4];
    const float* bx1 = (const float*)d_in[5];
    const float* Wx2 = (const float*)d_in[6];
    const float* bx2 = (const float*)d_in[7];
    const float* Wh1 = (const float*)d_in[8];
    const float* bh1 = (const float*)d_in[9];
    const float* Wh2 = (const float*)d_in[10];
    const float* bh2 = (const float*)d_in[11];

    const int NFEAT = 128, NHID = 64;
    const int N = in_sizes[0] / NFEAT;       // 100000
    const int E = in_sizes[1] / 2;           // 1600000
    const int NBUCK = (N + BUCK_W - 1) >> BUCK_SHIFT;   // 782 (<=1024 required)

    float* out   = (float*)d_out;
    float* h_out = out;                          // [N,64]
    float* xhat  = out + (long long)N * NHID;    // [N,128]
    float* mhat  = xhat + (long long)N * NFEAT;  // [N,128]

    // workspace layout (8/16B-aligned chunks):
    //   adj[E] | rowStart[N+2 pad] | bucketCnt[1024] | bucketOff[1026 pad] |
    //   bucketCursor[1024] | dinv[N] | mbuf[N*64] (staging uint2[E] aliases here) | hbuf[N*64]
    char* wsb = (char*)d_ws;
    int*   adj       = (int*)wsb;        wsb += (size_t)E * 4;
    int*   rowStart  = (int*)wsb;        wsb += (size_t)(N + 2) * 4;
    int*   bucketCnt = (int*)wsb;        wsb += (size_t)MAXB * 4;
    int*   bucketOff = (int*)wsb;        wsb += (size_t)(MAXB + 2) * 4;
    int*   bucketCur = (int*)wsb;        wsb += (size_t)MAXB * 4;
    float* dinv      = (float*)wsb;      wsb += (size_t)N * 4;
    float* mbuf      = (float*)wsb;      wsb += (size_t)N * 64 * 4;
    float* hbuf      = (float*)wsb;
    uint2* staging   = (uint2*)mbuf;     // 12.8 MB, dead before mbuf's first write

    const int B = 256;
    const int gridN   = (N + B - 1) / B;
    const int gridG   = (N + 63) / 64;                    // gemm64 blocks (64 rows each)
    const int gridMLP = (N + 31) / 32;                    // mlp2 blocks (32 rows each)
    const int gridGa  = ((N * 16) + B - 1) / B;           // gather4 blocks
    const int gridEm  = (E + EMIT_CHUNK - 1) / EMIT_CHUNK;

    const int* srcp = ei;
    const int* dstp = ei + E;

    // ---- CSR build (two-level counting sort) ----
    hipMemsetAsync(bucketCnt, 0, (size_t)MAXB * 4, stream);
    bucket_count<<<256, 256, 0, stream>>>(dstp, bucketCnt, E, NBUCK);
    bucket_scan<<<1, 1024, 0, stream>>>(bucketCnt, bucketOff, bucketCur, NBUCK, E);
    bucket_emit<<<gridEm, 256, 0, stream>>>(srcp, dstp, bucketCur, staging, E, NBUCK);
    bucket_sort<<<NBUCK, 256, 0, stream>>>(staging, bucketOff, rowStart, adj, N, NBUCK, E);
    dinv_kernel<<<gridN, B, 0, stream>>>(rowStart, dinv, N);

    // ---- layer 1: m = x@W1 ; h1 = relu(gather_combine(m)) ----
    gemm64<128><<<gridG, B, 0, stream>>>(x, W1, mbuf, N);
    gather_combine4<1><<<gridGa, B, 0, stream>>>((const float4*)mbuf, rowStart, adj, dinv,
                                                 (float4*)hbuf, N);

    // ---- layer 2: m = h1@W2 ; h = gather_combine(m) -> d_out ----
    gemm64<64><<<gridG, B, 0, stream>>>(hbuf, W2, mbuf, N);
    gather_combine4<0><<<gridGa, B, 0, stream>>>((const float4*)mbuf, rowStart, adj, dinv,
                                                 (float4*)h_out, N);

    // ---- neighbor mean of h -> mbuf (reused) ----
    gather_mean4<<<gridGa, B, 0, stream>>>((const float4*)h_out, rowStart, adj,
                                           (float4*)mbuf, N);

    // ---- decoders ----
    mlp2_kernel<<<gridMLP, B, 0, stream>>>(h_out, Wx1, bx1, Wx2, bx2, xhat, N);
    mlp2_kernel<<<gridMLP, B, 0, stream>>>(mbuf, Wh1, bh1, Wh2, bh2, mhat, N);
}

// Round 2
// 661.552 us; speedup vs baseline: 1.1530x; 1.0989x over previous
//
#include <hip/hip_runtime.h>

// 2-layer GCN encoder + 2 MLP decoders.
//   N = 100000, E = 1600000, NFEAT = 128, NHID = 64, DEC_HID = 128
// Outputs: h [N,64] | x_hat [N,128] | m_hat [N,128], fp32, concatenated in d_out.
//
// R3: CSR gather replaced scatter atomics: 1615 -> 1131 us.
// R4: hierarchical scan: 1131 -> 918 us.
// R5: two-level LDS counting sort for CSR build; float4 gathers. 918 -> 762 us.
// R6: 4x4 register-tiled fp32 GEMMs: 762 -> 727. mlp2 115 -> 104 us but went
//     latency-bound (VALUBusy 78 -> 41%): 1 L2 weight load per 16 FMA, only
//     4 in flight.
// R7: mlp2 -> 8x4 tile (32 FMA per weight load), unroll 8 (8 loads in flight),
//     both decoders fused into one dual-grid launch.

#define BUCK_SHIFT 7
#define BUCK_W 128
#define MAXB 1024
#define EMIT_CHUNK 8192

// ---------------- CSR build: two-level counting sort ----------------

// K1: per-bucket edge counts (LDS-aggregated histogram)
__global__ __launch_bounds__(256) void bucket_count(const int* __restrict__ dst,
                                                    int* __restrict__ bucketCnt,
                                                    int E, int NBUCK) {
    __shared__ int h[MAXB];
    for (int i = threadIdx.x; i < NBUCK; i += 256) h[i] = 0;
    __syncthreads();
    for (long long e = (long long)blockIdx.x * blockDim.x + threadIdx.x; e < E;
         e += (long long)gridDim.x * blockDim.x)
        atomicAdd(&h[dst[e] >> BUCK_SHIFT], 1);
    __syncthreads();
    for (int i = threadIdx.x; i < NBUCK; i += 256)
        if (h[i]) atomicAdd(&bucketCnt[i], h[i]);
}

// K2: exclusive scan of bucket counts (NBUCK <= 1024)
__global__ __launch_bounds__(1024) void bucket_scan(const int* __restrict__ cnt,
                                                    int* __restrict__ off,
                                                    int* __restrict__ cur,
                                                    int NBUCK, int E) {
    __shared__ int s[1024];
    const int t = threadIdx.x;
    int v = (t < NBUCK) ? cnt[t] : 0;
    s[t] = v;
    __syncthreads();
    for (int o = 1; o < 1024; o <<= 1) {
        int u = (t >= o) ? s[t - o] : 0;
        __syncthreads();
        s[t] += u;
        __syncthreads();
    }
    if (t < NBUCK) { off[t] = s[t] - v; cur[t] = s[t] - v; }
    if (t == 0) off[NBUCK] = E;
}

// K3: emit (src,dst) pairs into bucket-ordered staging with block-reserved runs
__global__ __launch_bounds__(256) void bucket_emit(const int* __restrict__ src,
                                                   const int* __restrict__ dst,
                                                   int* __restrict__ bucketCursor,
                                                   uint2* __restrict__ staging,
                                                   int E, int NBUCK) {
    __shared__ int h[MAXB];
    const int t = threadIdx.x;
    const long long base = (long long)blockIdx.x * EMIT_CHUNK;
    for (int i = t; i < NBUCK; i += 256) h[i] = 0;
    __syncthreads();
#pragma unroll
    for (int i = 0; i < EMIT_CHUNK / 256; ++i) {
        long long e = base + t + i * 256;
        if (e < E) atomicAdd(&h[dst[e] >> BUCK_SHIFT], 1);
    }
    __syncthreads();
    for (int i = t; i < NBUCK; i += 256) {
        int c = h[i];
        h[i] = c ? atomicAdd(&bucketCursor[i], c) : 0;
    }
    __syncthreads();
#pragma unroll
    for (int i = 0; i < EMIT_CHUNK / 256; ++i) {
        long long e = base + t + i * 256;
        if (e < E) {
            int d = dst[e];
            int pos = atomicAdd(&h[d >> BUCK_SHIFT], 1);
            staging[pos] = make_uint2((unsigned)src[e], (unsigned)d);
        }
    }
}

// K4: per-bucket counting sort -> rowStart + adj (one block per bucket)
__global__ __launch_bounds__(256) void bucket_sort(const uint2* __restrict__ staging,
                                                   const int* __restrict__ bucketOff,
                                                   int* __restrict__ rowStart,
                                                   int* __restrict__ adj,
                                                   int N, int NBUCK, int E) {
    __shared__ int h[BUCK_W];
    __shared__ int cur[BUCK_W];
    const int b = blockIdx.x;
    const int t = threadIdx.x;
    const int lo = b << BUCK_SHIFT;
    const int off = bucketOff[b];
    const int M = bucketOff[b + 1] - off;
    if (t < BUCK_W) h[t] = 0;
    __syncthreads();
    for (int i = t; i < M; i += 256)
        atomicAdd(&h[(int)staging[off + i].y - lo], 1);
    __syncthreads();
    if (t < BUCK_W) cur[t] = h[t];
    __syncthreads();
    for (int o = 1; o < BUCK_W; o <<= 1) {
        int u = 0;
        if (t < BUCK_W && t >= o) u = cur[t - o];
        __syncthreads();
        if (t < BUCK_W) cur[t] += u;
        __syncthreads();
    }
    if (t < BUCK_W) {
        int ex = off + cur[t] - h[t];     // exclusive prefix within bucket
        int d = lo + t;
        if (d < N) rowStart[d] = ex;
        cur[t] = ex;
    }
    if (b == 0 && t == 0) rowStart[N] = E;
    __syncthreads();
    for (int i = t; i < M; i += 256) {
        uint2 p = staging[off + i];
        int pos = atomicAdd(&cur[(int)p.y - lo], 1);
        adj[pos] = (int)p.x;
    }
}

__global__ void dinv_kernel(const int* __restrict__ rowStart, float* __restrict__ dinv, int N) {
    int i = blockIdx.x * blockDim.x + threadIdx.x;
    if (i < N) {
        int deg = rowStart[i + 1] - rowStart[i];
        dinv[i] = rsqrtf((float)deg + 1.0f);
    }
}

// ---------------- GEMM: out[N,64] = A[N,K] @ W[K,64] ----------------
// 64 rows x 64 cols per block; each thread owns a 4x4 register tile.
// As padded to K+1 so the 4 row-group broadcast reads hit distinct banks.
template <int K>
__global__ __launch_bounds__(256) void gemm64(const float* __restrict__ A,
                                              const float* __restrict__ W,
                                              float* __restrict__ out, int N) {
    const int tx = threadIdx.x;
    const int c4 = (tx & 15) << 2;        // output col base 0..60
    const int rg = (tx >> 4) << 2;        // row base within tile 0..60
    const int row0 = blockIdx.x * 64;
    __shared__ float As[64][K + 1];
    constexpr int C4 = K / 4;             // float4 per row
    for (int idx = tx; idx < 64 * C4; idx += 256) {
        int r = idx / C4, c = idx - r * C4;
        int row = row0 + r;
        float4 v = (row < N) ? ((const float4*)A)[(long long)row * C4 + c]
                             : make_float4(0.f, 0.f, 0.f, 0.f);
        As[r][c * 4 + 0] = v.x;
        As[r][c * 4 + 1] = v.y;
        As[r][c * 4 + 2] = v.z;
        As[r][c * 4 + 3] = v.w;
    }
    __syncthreads();
    float acc[4][4];
#pragma unroll
    for (int r = 0; r < 4; ++r)
#pragma unroll
        for (int j = 0; j < 4; ++j) acc[r][j] = 0.f;
#pragma unroll 8
    for (int k = 0; k < K; ++k) {
        float4 w = *(const float4*)&W[k * 64 + c4];
        float a0 = As[rg + 0][k];
        float a1 = As[rg + 1][k];
        float a2 = As[rg + 2][k];
        float a3 = As[rg + 3][k];
        acc[0][0] += a0 * w.x; acc[0][1] += a0 * w.y; acc[0][2] += a0 * w.z; acc[0][3] += a0 * w.w;
        acc[1][0] += a1 * w.x; acc[1][1] += a1 * w.y; acc[1][2] += a1 * w.z; acc[1][3] += a1 * w.w;
        acc[2][0] += a2 * w.x; acc[2][1] += a2 * w.y; acc[2][2] += a2 * w.z; acc[2][3] += a2 * w.w;
        acc[3][0] += a3 * w.x; acc[3][1] += a3 * w.y; acc[3][2] += a3 * w.z; acc[3][3] += a3 * w.w;
    }
#pragma unroll
    for (int r = 0; r < 4; ++r) {
        int row = row0 + rg + r;
        if (row < N)
            *(float4*)&out[(long long)row * 64 + c4] =
                make_float4(acc[r][0], acc[r][1], acc[r][2], acc[r][3]);
    }
}

// ---------------- GCN aggregation by gather, float4 lanes ----------------
// 16 lanes per dst row (lane l owns features 4l..4l+3).
// out = dinv[d]*(m[d]*dinv[d] + sum m[s]*dinv[s])
template <int RELU>
__global__ __launch_bounds__(256) void gather_combine4(const float4* __restrict__ m4,
                                                       const int* __restrict__ rowStart,
                                                       const int* __restrict__ adj,
                                                       const float* __restrict__ dinv,
                                                       float4* __restrict__ out4, int N) {
    int gid = blockIdx.x * 256 + threadIdx.x;
    int d = gid >> 4;
    if (d >= N) return;
    int l = gid & 15;
    int start = rowStart[d], end = rowStart[d + 1];
    float dv = dinv[d];
    float4 ms = m4[(long long)d * 16 + l];
    float4 a0, a1;
    a0.x = ms.x * dv; a0.y = ms.y * dv; a0.z = ms.z * dv; a0.w = ms.w * dv;
    a1.x = 0.f; a1.y = 0.f; a1.z = 0.f; a1.w = 0.f;
    int t = start;
    for (; t + 2 <= end; t += 2) {
        int s0 = adj[t], s1 = adj[t + 1];
        float w0 = dinv[s0], w1 = dinv[s1];
        float4 v0 = m4[(long long)s0 * 16 + l];
        float4 v1 = m4[(long long)s1 * 16 + l];
        a0.x += v0.x * w0; a0.y += v0.y * w0; a0.z += v0.z * w0; a0.w += v0.w * w0;
        a1.x += v1.x * w1; a1.y += v1.y * w1; a1.z += v1.z * w1; a1.w += v1.w * w1;
    }
    if (t < end) {
        int s = adj[t];
        float w = dinv[s];
        float4 v = m4[(long long)s * 16 + l];
        a0.x += v.x * w; a0.y += v.y * w; a0.z += v.z * w; a0.w += v.w * w;
    }
    float4 r;
    r.x = (a0.x + a1.x) * dv; r.y = (a0.y + a1.y) * dv;
    r.z = (a0.z + a1.z) * dv; r.w = (a0.w + a1.w) * dv;
    if (RELU) {
        r.x = fmaxf(r.x, 0.f); r.y = fmaxf(r.y, 0.f);
        r.z = fmaxf(r.z, 0.f); r.w = fmaxf(r.w, 0.f);
    }
    out4[(long long)d * 16 + l] = r;
}

// neighbor mean: out = (sum_{s in N(d)} h[s]) / max(deg,1)
__global__ __launch_bounds__(256) void gather_mean4(const float4* __restrict__ h4,
                                                    const int* __restrict__ rowStart,
                                                    const int* __restrict__ adj,
                                                    float4* __restrict__ out4, int N) {
    int gid = blockIdx.x * 256 + threadIdx.x;
    int d = gid >> 4;
    if (d >= N) return;
    int l = gid & 15;
    int start = rowStart[d], end = rowStart[d + 1];
    int deg = end - start;
    float4 a0, a1;
    a0.x = 0.f; a0.y = 0.f; a0.z = 0.f; a0.w = 0.f;
    a1 = a0;
    int t = start;
    for (; t + 2 <= end; t += 2) {
        int s0 = adj[t], s1 = adj[t + 1];
        float4 v0 = h4[(long long)s0 * 16 + l];
        float4 v1 = h4[(long long)s1 * 16 + l];
        a0.x += v0.x; a0.y += v0.y; a0.z += v0.z; a0.w += v0.w;
        a1.x += v1.x; a1.y += v1.y; a1.z += v1.z; a1.w += v1.w;
    }
    if (t < end) {
        float4 v = h4[(long long)adj[t] * 16 + l];
        a0.x += v.x; a0.y += v.y; a0.z += v.z; a0.w += v.w;
    }
    float inv = 1.0f / (float)max(deg, 1);
    float4 r;
    r.x = (a0.x + a1.x) * inv; r.y = (a0.y + a1.y) * inv;
    r.z = (a0.z + a1.z) * inv; r.w = (a0.w + a1.w) * inv;
    out4[(long long)d * 16 + l] = r;
}

// ---------------- fused 2-layer MLP: out = relu(In@Wa + ba) @ Wb + bb ----------------
// Dual-grid: blockIdx.y picks decoder {x_hat, m_hat}. 64 rows x 128 cols per
// block, 256 threads, 8x4 register tile per thread: 32 FMA per float4 weight
// load, unroll 8 -> 8 weight loads in flight. LDS broadcast reads are 2
// distinct addresses per wave (free).
__global__ __launch_bounds__(256) void mlp2_dual(const float* __restrict__ In0,
                                                 const float* __restrict__ In1,
                                                 const float* __restrict__ Wa0,
                                                 const float* __restrict__ ba0,
                                                 const float* __restrict__ Wb0,
                                                 const float* __restrict__ bb0,
                                                 const float* __restrict__ Wa1,
                                                 const float* __restrict__ ba1,
                                                 const float* __restrict__ Wb1,
                                                 const float* __restrict__ bb1,
                                                 float* __restrict__ out0,
                                                 float* __restrict__ out1, int N) {
    const int which = blockIdx.y;
    const float* In = which ? In1 : In0;
    const float* Wa = which ? Wa1 : Wa0;
    const float* ba = which ? ba1 : ba0;
    const float* Wb = which ? Wb1 : Wb0;
    const float* bb = which ? bb1 : bb0;
    float* out = which ? out1 : out0;

    const int tx = threadIdx.x;
    const int c4 = (tx & 31) << 2;       // output col base 0..124
    const int rg = (tx >> 5) << 3;       // row base within tile 0..56 (8 rows)
    const int row0 = blockIdx.x * 64;
    __shared__ float ins[64][64];        // 16 KB
    __shared__ float t[64][128];         // 32 KB
    for (int idx = tx; idx < 64 * 16; idx += 256) {
        int r = idx >> 4, c = idx & 15;
        int row = row0 + r;
        float4 v = (row < N) ? ((const float4*)In)[(long long)row * 16 + c]
                             : make_float4(0.f, 0.f, 0.f, 0.f);
        *(float4*)&ins[r][c * 4] = v;
    }
    __syncthreads();
    float acc[8][4];
    float4 b1 = *(const float4*)&ba[c4];
#pragma unroll
    for (int r = 0; r < 8; ++r) {
        acc[r][0] = b1.x; acc[r][1] = b1.y; acc[r][2] = b1.z; acc[r][3] = b1.w;
    }
#pragma unroll 8
    for (int k = 0; k < 64; ++k) {
        float4 w = *(const float4*)&Wa[k * 128 + c4];
#pragma unroll
        for (int r = 0; r < 8; ++r) {
            float a = ins[rg + r][k];
            acc[r][0] += a * w.x; acc[r][1] += a * w.y;
            acc[r][2] += a * w.z; acc[r][3] += a * w.w;
        }
    }
#pragma unroll
    for (int r = 0; r < 8; ++r)
        *(float4*)&t[rg + r][c4] = make_float4(fmaxf(acc[r][0], 0.f), fmaxf(acc[r][1], 0.f),
                                               fmaxf(acc[r][2], 0.f), fmaxf(acc[r][3], 0.f));
    __syncthreads();
    float4 b2 = *(const float4*)&bb[c4];
#pragma unroll
    for (int r = 0; r < 8; ++r) {
        acc[r][0] = b2.x; acc[r][1] = b2.y; acc[r][2] = b2.z; acc[r][3] = b2.w;
    }
#pragma unroll 8
    for (int k = 0; k < 128; ++k) {
        float4 w = *(const float4*)&Wb[k * 128 + c4];
#pragma unroll
        for (int r = 0; r < 8; ++r) {
            float a = t[rg + r][k];
            acc[r][0] += a * w.x; acc[r][1] += a * w.y;
            acc[r][2] += a * w.z; acc[r][3] += a * w.w;
        }
    }
#pragma unroll
    for (int r = 0; r < 8; ++r) {
        int row = row0 + rg + r;
        if (row < N)
            *(float4*)&out[(long long)row * 128 + c4] =
                make_float4(acc[r][0], acc[r][1], acc[r][2], acc[r][3]);
    }
}

extern "C" void kernel_launch(void* const* d_in, const int* in_sizes, int n_in,
                              void* d_out, int out_size, void* d_ws, size_t ws_size,
                              hipStream_t stream) {
    const float* x   = (const float*)d_in[0];
    const int*   ei  = (const int*)  d_in[1];
    const float* W1  = (const float*)d_in[2];
    const float* W2  = (const float*)d_in[3];
    const float* Wx1 = (const float*)d_in[4];
    const float* bx1 = (const float*)d_in[5];
    const float* Wx2 = (const float*)d_in[6];
    const float* bx2 = (const float*)d_in[7];
    const float* Wh1 = (const float*)d_in[8];
    const float* bh1 = (const float*)d_in[9];
    const float* Wh2 = (const float*)d_in[10];
    const float* bh2 = (const float*)d_in[11];

    const int NFEAT = 128, NHID = 64;
    const int N = in_sizes[0] / NFEAT;       // 100000
    const int E = in_sizes[1] / 2;           // 1600000
    const int NBUCK = (N + BUCK_W - 1) >> BUCK_SHIFT;   // 782 (<=1024 required)

    float* out   = (float*)d_out;
    float* h_out = out;                          // [N,64]
    float* xhat  = out + (long long)N * NHID;    // [N,128]
    float* mhat  = xhat + (long long)N * NFEAT;  // [N,128]

    // workspace layout (8/16B-aligned chunks):
    //   adj[E] | rowStart[N+2 pad] | bucketCnt[1024] | bucketOff[1026 pad] |
    //   bucketCursor[1024] | dinv[N] | mbuf[N*64] (staging uint2[E] aliases here) | hbuf[N*64]
    char* wsb = (char*)d_ws;
    int*   adj       = (int*)wsb;        wsb += (size_t)E * 4;
    int*   rowStart  = (int*)wsb;        wsb += (size_t)(N + 2) * 4;
    int*   bucketCnt = (int*)wsb;        wsb += (size_t)MAXB * 4;
    int*   bucketOff = (int*)wsb;        wsb += (size_t)(MAXB + 2) * 4;
    int*   bucketCur = (int*)wsb;        wsb += (size_t)MAXB * 4;
    float* dinv      = (float*)wsb;      wsb += (size_t)N * 4;
    float* mbuf      = (float*)wsb;      wsb += (size_t)N * 64 * 4;
    float* hbuf      = (float*)wsb;
    uint2* staging   = (uint2*)mbuf;     // 12.8 MB, dead before mbuf's first write

    const int B = 256;
    const int gridN   = (N + B - 1) / B;
    const int gridG   = (N + 63) / 64;                    // gemm64 blocks (64 rows each)
    const int gridGa  = ((N * 16) + B - 1) / B;           // gather4 blocks
    const int gridEm  = (E + EMIT_CHUNK - 1) / EMIT_CHUNK;
    dim3 gridMLP((N + 63) / 64, 2);                       // dual decoder

    const int* srcp = ei;
    const int* dstp = ei + E;

    // ---- CSR build (two-level counting sort) ----
    hipMemsetAsync(bucketCnt, 0, (size_t)MAXB * 4, stream);
    bucket_count<<<256, 256, 0, stream>>>(dstp, bucketCnt, E, NBUCK);
    bucket_scan<<<1, 1024, 0, stream>>>(bucketCnt, bucketOff, bucketCur, NBUCK, E);
    bucket_emit<<<gridEm, 256, 0, stream>>>(srcp, dstp, bucketCur, staging, E, NBUCK);
    bucket_sort<<<NBUCK, 256, 0, stream>>>(staging, bucketOff, rowStart, adj, N, NBUCK, E);
    dinv_kernel<<<gridN, B, 0, stream>>>(rowStart, dinv, N);

    // ---- layer 1: m = x@W1 ; h1 = relu(gather_combine(m)) ----
    gemm64<128><<<gridG, B, 0, stream>>>(x, W1, mbuf, N);
    gather_combine4<1><<<gridGa, B, 0, stream>>>((const float4*)mbuf, rowStart, adj, dinv,
                                                 (float4*)hbuf, N);

    // ---- layer 2: m = h1@W2 ; h = gather_combine(m) -> d_out ----
    gemm64<64><<<gridG, B, 0, stream>>>(hbuf, W2, mbuf, N);
    gather_combine4<0><<<gridGa, B, 0, stream>>>((const float4*)mbuf, rowStart, adj, dinv,
                                                 (float4*)h_out, N);

    // ---- neighbor mean of h -> mbuf (reused) ----
    gather_mean4<<<gridGa, B, 0, stream>>>((const float4*)h_out, rowStart, adj,
                                           (float4*)mbuf, N);

    // ---- decoders (fused dual launch) ----
    mlp2_dual<<<gridMLP, B, 0, stream>>>(h_out, mbuf,
                                         Wx1, bx1, Wx2, bx2,
                                         Wh1, bh1, Wh2, bh2,
                                         xhat, mhat, N);
}